// Round 8
// baseline (34.218 us; speedup 1.0000x reference)
//
#include <hip/hip_runtime.h>
#include <math.h>

#define MAX_COV 10000.0f
#define MIN_COV 0.0001f
#define SYMM_THRESH 1e-05f
#define DET_THRESH 1e-06f
#define MAX_POS 1000.0f
#define EIG_CLAMP 0.0001f
#define INV_EPS 0.0001f

namespace {
constexpr int BS = 256;

typedef float v2f __attribute__((ext_vector_type(2)));
// dword-aligned vector types: multi-dword global loads need only 4B alignment on CDNA
typedef float f32x4 __attribute__((ext_vector_type(4), aligned(4)));
typedef float f32x2 __attribute__((ext_vector_type(2), aligned(4)));

__device__ __forceinline__ v2f mk2(float a, float b) { v2f r; r[0] = a; r[1] = b; return r; }

__device__ __forceinline__ float rcp_fast(float x)  { return __builtin_amdgcn_rcpf(x); }
__device__ __forceinline__ float sqrt_fast(float x) { return __builtin_amdgcn_sqrtf(x); }

// acos(x)/3 via A&S 4.4.45 with 1/3 folded into the coefficients.
__device__ __forceinline__ float acos3_fast(float x) {
    const float t = fabsf(x);
    const float s = sqrt_fast(fmaxf(1.0f - t, 0.0f));
    float p = fmaf(t, -0.00624310f, 0.02475367f);
    p = fmaf(t, p, -0.07070480f);
    p = fmaf(t, p, 0.52357627f);
    const float a3 = s * p;                       // acos(|x|)/3
    return (x >= 0.0f) ? a3 : (1.0471975512f - a3); // pi/3 - a3
}

// Closed-form eigenvalues of a symmetric 3x3 (trig method).
__device__ __forceinline__ void eigvals3(
    float m00, float m01, float m02, float m11, float m12, float m22,
    float& l1, float& l2, float& l3)
{
    const float q   = (m00 + m11 + m22) * (1.0f / 3.0f);
    const float b00 = m00 - q, b11 = m11 - q, b22 = m22 - q;
    const float offsq = m01 * m01 + m02 * m02 + m12 * m12;
    const float p2  = b00 * b00 + b11 * b11 + b22 * b22 + 2.0f * offsq;
    const float p   = sqrt_fast(p2 * (1.0f / 6.0f));
    const float detB =
          b00 * (b11 * b22 - m12 * m12)
        - m01 * (m01 * b22 - m12 * m02)
        + m02 * (m01 * m12 - b11 * m02);
    const float pinv  = rcp_fast(fmaxf(p, 1e-30f));
    const float pinv3 = pinv * pinv * pinv;       // computed in parallel with detB
    // p==0 (masked identity) -> detB==0 -> 0*inf = NaN; the clamp below drops
    // NaN (v_max/v_min are IEEE maxNum/minNum) -> r=-1 -> eigvals = q. Correct.
    float r = (0.5f * detB) * pinv3;
    r = fminf(1.0f, fmaxf(-1.0f, r));
    const float phi = acos3_fast(r);              // [0, pi/3]
    const float c   = __cosf(phi);                // parallel trans ops
    const float s   = __sinf(phi);                // (phi small: no range issues)
    l1 = q + 2.0f * p * c;
    l3 = q + p * (-c - 1.7320508075688772f * s);  // cos(phi+2pi/3) identity
    l2 = 3.0f * q - l1 - l3;
}

__global__ __launch_bounds__(BS, 4)
void wl_kernel(const float* __restrict__ miu1, const float* __restrict__ miu2,
               const float* __restrict__ cov1, const float* __restrict__ cov2,
               float* __restrict__ out, int N)
{
    const int i = blockIdx.x * BS + threadIdx.x;
    if (i >= N) return;

    // ---- vectorized loads: 9 floats = dwordx4 + dwordx4 + dword (3 VMEM) ----
    const float* p1 = cov1 + (size_t)i * 9;
    const float* p2 = cov2 + (size_t)i * 9;
    const f32x4 a0 = *(const f32x4*)(p1);
    const f32x4 a1 = *(const f32x4*)(p1 + 4);
    const float a2 = p1[8];
    const f32x4 b0 = *(const f32x4*)(p2);
    const f32x4 b1 = *(const f32x4*)(p2 + 4);
    const float b2 = p2[8];
    const float c1[9]  = { a0[0], a0[1], a0[2], a0[3], a1[0], a1[1], a1[2], a1[3], a2 };
    const float c2r[9] = { b0[0], b0[1], b0[2], b0[3], b1[0], b1[1], b1[2], b1[3], b2 };

    const float* q1p = miu1 + (size_t)i * 3;
    const float* q2p = miu2 + (size_t)i * 3;
    const f32x2 m1v = *(const f32x2*)(q1p);
    const float m1z = q1p[2];
    const f32x2 m2v = *(const f32x2*)(q2p);
    const float m2z = q2p[2];
    const float u1[3] = { m1v[0], m1v[1], m1z };
    const float u2[3] = { m2v[0], m2v[1], m2z };

    // ---- stability mask (abs folds into VOP3 input modifiers) ----
    float amax1 = 0.0f, amax2 = 0.0f, amin1 = 1e30f, amin2 = 1e30f;
    #pragma unroll
    for (int k = 0; k < 9; ++k) {
        amax1 = fmaxf(amax1, fabsf(c1[k]));  amin1 = fminf(amin1, fabsf(c1[k]));
        amax2 = fmaxf(amax2, fabsf(c2r[k])); amin2 = fminf(amin2, fabsf(c2r[k]));
    }
    bool ok = (amax1 < MAX_COV) && (amax2 < MAX_COV)
           && (amin1 > MIN_COV) && (amin2 > MIN_COV);
    const float sd = fmaxf(fmaxf(fabsf(c1[1] - c1[3]), fabsf(c1[2] - c1[6])),
                    fmaxf(fabsf(c1[5] - c1[7]),
                    fmaxf(fmaxf(fabsf(c2r[1] - c2r[3]), fabsf(c2r[2] - c2r[6])),
                          fabsf(c2r[5] - c2r[7]))));
    ok = ok && (sd < SYMM_THRESH);
    const float det1 = c1[0] * (c1[4] * c1[8] - c1[5] * c1[7])
                     - c1[1] * (c1[3] * c1[8] - c1[5] * c1[6])
                     + c1[2] * (c1[3] * c1[7] - c1[4] * c1[6]);
    const float det2 = c2r[0] * (c2r[4] * c2r[8] - c2r[5] * c2r[7])
                     - c2r[1] * (c2r[3] * c2r[8] - c2r[5] * c2r[6])
                     + c2r[2] * (c2r[3] * c2r[7] - c2r[4] * c2r[6]);
    ok = ok && (fabsf(det1) > DET_THRESH) && (fabsf(det2) > DET_THRESH);
    const float um = fmaxf(fmaxf(fmaxf(fabsf(u1[0]), fabsf(u1[1])), fabsf(u1[2])),
                           fmaxf(fmaxf(fabsf(u2[0]), fabsf(u2[1])), fabsf(u2[2])));
    ok = ok && (um < MAX_POS);

    // ---- symmetrized inputs (packed adds); masked items -> identity ----
    const v2f md01 = 0.5f * (mk2(c1[1], c2r[1]) + mk2(c1[3], c2r[3]));
    const v2f md02 = 0.5f * (mk2(c1[2], c2r[2]) + mk2(c1[6], c2r[6]));
    const v2f md12 = 0.5f * (mk2(c1[5], c2r[5]) + mk2(c1[7], c2r[7]));
    const float m00 = ok ? c1[0] : 1.0f;
    const float m11 = ok ? c1[4] : 1.0f;
    const float m22 = ok ? c1[8] : 1.0f;
    const float m01 = ok ? md01[0] : 0.0f;
    const float m02 = ok ? md02[0] : 0.0f;
    const float m12 = ok ? md12[0] : 0.0f;
    const float d00 = ok ? c2r[0] : 1.0f;
    const float d11 = ok ? c2r[4] : 1.0f;
    const float d22 = ok ? c2r[8] : 1.0f;
    const float d01 = ok ? md01[1] : 0.0f;
    const float d02 = ok ? md02[1] : 0.0f;
    const float d12 = ok ? md12[1] : 0.0f;

    float l1, l2, l3;
    eigvals3(m00, m01, m02, m11, m12, m22, l1, l2, l3);
    l1 = fmaxf(l1, EIG_CLAMP); l2 = fmaxf(l2, EIG_CLAMP); l3 = fmaxf(l3, EIG_CLAMP);
    const float sa = sqrt_fast(l1), sb = sqrt_fast(l2), sc = sqrt_fast(l3);
    const float i_ab = rcp_fast(sa + sb);
    const float i_bc = rcp_fast(sb + sc);
    const float i_ac = rcp_fast(sa + sc);
    const float ea = rcp_fast(INV_EPS + sa);
    const float eb = rcp_fast(INV_EPS + sb);
    const float ec = rcp_fast(INV_EPS + sc);
    // Newton coefficients for f=sqrt (q*) and f=1/(eps+sqrt) (g*), packed.
    const v2f qg0 = mk2(sa, ea);
    const v2f qg1 = mk2(i_ab, -ea * eb * i_ab);
    const v2f qg2 = mk2(-i_ab * i_bc * i_ac,
                        (INV_EPS + sa + sb + sc) * ea * eb * ec * i_ab * i_bc * i_ac);

    // U = M - l1*I, V = M - l2*I, P = U*V (symmetric); packed pairs
    const float u00 = m00 - l1, u11 = m11 - l1, u22 = m22 - l1;
    const float v00 = m00 - l2, v11 = m11 - l2, v22 = m22 - l2;
    const v2f PA = u00 * mk2(v00, m01) + m01 * mk2(m01, v11) + m02 * mk2(m02, m12); // P00,P01
    const v2f PB = mk2(u00, m01) * mk2(m02, m01) + mk2(m01, u11) * mk2(m12, v11)
                 + mk2(m02, m12) * mk2(v22, m12);                                    // P02,P11
    const v2f PC = mk2(m01, m02) * mk2(m02, m02) + mk2(u11, m12) * mk2(m12, m12)
                 + mk2(m12, u22) * mk2(v22, v22);                                    // P12,P22

    // A_sqrt (S) and A_sqrt_inv (G) share the Newton basis: pack (S_ij, G_ij)
    const v2f SG00 = qg0 + qg1 * u00 + qg2 * PA[0];
    const v2f SG01 =       qg1 * m01 + qg2 * PA[1];
    const v2f SG02 =       qg1 * m02 + qg2 * PB[0];
    const v2f SG11 = qg0 + qg1 * u11 + qg2 * PB[1];
    const v2f SG12 =       qg1 * m12 + qg2 * PC[0];
    const v2f SG22 = qg0 + qg1 * u22 + qg2 * PC[1];
    const float S00 = SG00[0], G00 = SG00[1];
    const float S01 = SG01[0], G01 = SG01[1];
    const float S02 = SG02[0], G02 = SG02[1];
    const float S11 = SG11[0], G11 = SG11[1];
    const float S12 = SG12[0], G12 = SG12[1];
    const float S22 = SG22[0], G22 = SG22[1];

    // T = S*D (full), C = T*S (6 unique) — packed
    const v2f TA = S00 * mk2(d00, d01) + S01 * mk2(d01, d11) + S02 * mk2(d02, d12); // T00,T01
    const v2f TB = mk2(S00, S01) * mk2(d02, d00) + mk2(S01, S11) * mk2(d12, d01)
                 + mk2(S02, S12) * mk2(d22, d02);                                    // T02,T10
    const v2f TC = S01 * mk2(d01, d02) + S11 * mk2(d11, d12) + S12 * mk2(d12, d22); // T11,T12
    const v2f TD = S02 * mk2(d00, d01) + S12 * mk2(d01, d11) + S22 * mk2(d02, d12); // T20,T21
    const float T00 = TA[0], T01 = TA[1], T02 = TB[0], T10 = TB[1];
    const float T11 = TC[0], T12 = TC[1], T20 = TD[0], T21 = TD[1];
    const float T22 = S02 * d02 + S12 * d12 + S22 * d22;

    const v2f CA = T00 * mk2(S00, S01) + T01 * mk2(S01, S11) + T02 * mk2(S02, S12); // C00,C01
    const v2f CB = mk2(T00, T10) * mk2(S02, S01) + mk2(T01, T11) * mk2(S12, S11)
                 + mk2(T02, T12) * mk2(S22, S12);                                    // C02,C11
    const v2f CC = mk2(T10, T20) * S02 + mk2(T11, T21) * S12 + mk2(T12, T22) * S22; // C12,C22
    const float C00 = CA[0], C01 = CA[1], C02 = CB[0];
    const float C11 = CB[1], C12 = CC[0], C22 = CC[1];

    // C_sqrt: f(lambda) = sqrt(|lambda|)
    float e1, e2, e3;
    eigvals3(C00, C01, C02, C11, C12, C22, e1, e2, e3);
    const float ra = sqrt_fast(fabsf(e1));
    const float rb = sqrt_fast(fabsf(e2));
    const float rc = sqrt_fast(fabsf(e3));
    const float j_ab = rcp_fast(fmaxf(ra + rb, 1e-12f));
    const float j_bc = rcp_fast(fmaxf(rb + rc, 1e-12f));
    const float j_ac = rcp_fast(fmaxf(ra + rc, 1e-12f));
    const float h0 = ra, h1 = j_ab, h2 = -j_ab * j_bc * j_ac;
    const float cu00 = C00 - e1, cu11 = C11 - e1, cu22 = C22 - e1;
    const float cv00 = C00 - e2, cv11 = C11 - e2, cv22 = C22 - e2;
    const v2f RA = cu00 * mk2(cv00, C01) + C01 * mk2(C01, cv11) + C02 * mk2(C02, C12); // R00,R01
    const v2f RB = mk2(cu00, C01) * mk2(C02, C01) + mk2(C01, cu11) * mk2(C12, cv11)
                 + mk2(C02, C12) * mk2(cv22, C12);                                      // R02,R11
    const v2f RC = mk2(C01, C02) * mk2(C02, C02) + mk2(cu11, C12) * mk2(C12, C12)
                 + mk2(C12, cu22) * mk2(cv22, cv22);                                    // R12,R22

    const v2f XA = mk2(h0, 0.0f) + h1 * mk2(cu00, C01) + h2 * mk2(RA[0], RA[1]); // X00,X01
    const v2f XB = mk2(h0, 0.0f) + h1 * mk2(cu11, C02) + h2 * mk2(RB[1], RB[0]); // X11,X02
    const v2f XC = mk2(h0, 0.0f) + h1 * mk2(cu22, C12) + h2 * mk2(RC[1], RC[0]); // X22,X12
    const float X00 = XA[0], X01 = XA[1], X11 = XB[0], X02 = XB[1];
    const float X22 = XC[0], X12 = XC[1];

    // A = S * X, W = A * G — packed
    const v2f AA = S00 * mk2(X00, X01) + S01 * mk2(X01, X11) + S02 * mk2(X02, X12); // A00,A01
    const v2f AB = mk2(S00, S01) * mk2(X02, X00) + mk2(S01, S11) * mk2(X12, X01)
                 + mk2(S02, S12) * mk2(X22, X02);                                    // A02,A10
    const v2f AC = S01 * mk2(X01, X02) + S11 * mk2(X11, X12) + S12 * mk2(X12, X22); // A11,A12
    const v2f AD = S02 * mk2(X00, X01) + S12 * mk2(X01, X11) + S22 * mk2(X02, X12); // A20,A21
    const float A00 = AA[0], A01 = AA[1], A02 = AB[0], A10 = AB[1];
    const float A11 = AC[0], A12 = AC[1], A20 = AD[0], A21 = AD[1];
    const float A22 = S02 * X02 + S12 * X12 + S22 * X22;

    const v2f WA = A00 * mk2(G00, G01) + A01 * mk2(G01, G11) + A02 * mk2(G02, G12); // W0,W1
    const v2f WB = mk2(A00, A10) * mk2(G02, G00) + mk2(A01, A11) * mk2(G12, G01)
                 + mk2(A02, A12) * mk2(G22, G02);                                    // W2,W3
    const v2f WC = A10 * mk2(G01, G02) + A11 * mk2(G11, G12) + A12 * mk2(G12, G22); // W4,W5
    const v2f WD = A20 * mk2(G00, G01) + A21 * mk2(G01, G11) + A22 * mk2(G02, G12); // W6,W7
    const float W0 = WA[0], W1 = WA[1], W2 = WB[0], W3 = WB[1];
    const float W4 = WC[0], W5 = WC[1], W6 = WD[0], W7 = WD[1];
    const float W8 = A20 * G02 + A21 * G12 + A22 * G22;

    // cov_vel = W + W^T - 2*sym(cov_1): 6 unique entries, packed
    const v2f EA = mk2(W0, W1) + mk2(W0, W3) - 2.0f * mk2(m00, m01); // E00,E01
    const v2f EB = mk2(W2, W4) + mk2(W6, W4) - 2.0f * mk2(m02, m11); // E02,E11
    const v2f EC = mk2(W5, W8) + mk2(W7, W8) - 2.0f * mk2(m12, m22); // E12,E22

    const float E00 = ok ? EA[0] : 0.0f;
    const float E01 = ok ? EA[1] : 0.0f;
    const float E02 = ok ? EB[0] : 0.0f;
    const float E11 = ok ? EB[1] : 0.0f;
    const float E12 = ok ? EC[0] : 0.0f;
    const float E22 = ok ? EC[1] : 0.0f;

    // ---- vectorized nontemporal stores: dwordx4 + dwordx4 + dword ----
    float* out_cov = out + (size_t)N * 3;
    float* oc = out_cov + (size_t)i * 9;
    f32x4 o0; o0[0] = E00; o0[1] = E01; o0[2] = E02; o0[3] = E01;
    f32x4 o1; o1[0] = E11; o1[1] = E12; o1[2] = E02; o1[3] = E12;
    __builtin_nontemporal_store(o0, (f32x4*)oc);
    __builtin_nontemporal_store(o1, (f32x4*)(oc + 4));
    __builtin_nontemporal_store(E22, oc + 8);

    float* om = out + (size_t)i * 3;
    f32x2 mo; mo[0] = ok ? (u2[0] - u1[0]) : 0.0f;
              mo[1] = ok ? (u2[1] - u1[1]) : 0.0f;
    const float mz = ok ? (u2[2] - u1[2]) : 0.0f;
    __builtin_nontemporal_store(mo, (f32x2*)om);
    __builtin_nontemporal_store(mz, om + 2);
}

} // namespace

extern "C" void kernel_launch(void* const* d_in, const int* in_sizes, int n_in,
                              void* d_out, int out_size, void* d_ws, size_t ws_size,
                              hipStream_t stream)
{
    const float* miu1 = (const float*)d_in[0];
    const float* miu2 = (const float*)d_in[1];
    const float* cov1 = (const float*)d_in[2];
    const float* cov2 = (const float*)d_in[3];
    float* out = (float*)d_out;
    const int N = in_sizes[0] / 3;
    const int grid = (N + BS - 1) / BS;
    hipLaunchKernelGGL(wl_kernel, dim3(grid), dim3(BS), 0, stream,
                       miu1, miu2, cov1, cov2, out, N);
}

// Round 9
// 28.631 us; speedup vs baseline: 1.1952x; 1.1952x over previous
//
#include <hip/hip_runtime.h>
#include <math.h>

#define MAX_COV 10000.0f
#define MIN_COV 0.0001f
#define SYMM_THRESH 1e-05f
#define DET_THRESH 1e-06f
#define MAX_POS 1000.0f
#define EIG_CLAMP 0.0001f
#define INV_EPS 0.0001f

namespace {
constexpr int BS = 256;

typedef float v2f __attribute__((ext_vector_type(2)));
typedef float f32x4 __attribute__((ext_vector_type(4), aligned(4)));
typedef float f32x2 __attribute__((ext_vector_type(2), aligned(4)));

__device__ __forceinline__ v2f mk2(float a, float b) { v2f r; r[0] = a; r[1] = b; return r; }

__device__ __forceinline__ float rcp_fast(float x)  { return __builtin_amdgcn_rcpf(x); }
__device__ __forceinline__ float sqrt_fast(float x) { return __builtin_amdgcn_sqrtf(x); }

// acos(x)/3 via A&S 4.4.45 with 1/3 folded into the coefficients.
__device__ __forceinline__ float acos3_fast(float x) {
    const float t = fabsf(x);
    const float s = sqrt_fast(fmaxf(1.0f - t, 0.0f));
    float p = fmaf(t, -0.00624310f, 0.02475367f);
    p = fmaf(t, p, -0.07070480f);
    p = fmaf(t, p, 0.52357627f);
    const float a3 = s * p;                         // acos(|x|)/3
    return (x >= 0.0f) ? a3 : (1.0471975512f - a3); // pi/3 - a3
}

// Closed-form eigenvalues of a symmetric 3x3 (trig method).
// NaN-tolerant: garbage input (masked-out lanes) may produce NaN eigenvalues;
// downstream results are discarded at the final select.
__device__ __forceinline__ void eigvals3(
    float m00, float m01, float m02, float m11, float m12, float m22,
    float& l1, float& l2, float& l3)
{
    const float q   = (m00 + m11 + m22) * (1.0f / 3.0f);
    const float b00 = m00 - q, b11 = m11 - q, b22 = m22 - q;
    const float offsq = m01 * m01 + m02 * m02 + m12 * m12;
    const float p2  = b00 * b00 + b11 * b11 + b22 * b22 + 2.0f * offsq;
    const float p   = sqrt_fast(p2 * (1.0f / 6.0f));
    const float detB =
          b00 * (b11 * b22 - m12 * m12)
        - m01 * (m01 * b22 - m12 * m02)
        + m02 * (m01 * m12 - b11 * m02);
    const float pinv  = rcp_fast(fmaxf(p, 1e-30f));
    const float pinv3 = pinv * pinv * pinv;
    // NaN from 0*inf is dropped by the IEEE minNum/maxNum clamp below.
    float r = (0.5f * detB) * pinv3;
    r = fminf(1.0f, fmaxf(-1.0f, r));
    const float phi = acos3_fast(r);              // [0, pi/3]
    const float c   = __cosf(phi);
    const float s   = __sinf(phi);
    l1 = q + 2.0f * p * c;
    l3 = q + p * (-c - 1.7320508075688772f * s);  // cos(phi+2pi/3) identity
    l2 = 3.0f * q - l1 - l3;
}

__global__ __launch_bounds__(BS, 4)
void wl_kernel(const float* __restrict__ miu1, const float* __restrict__ miu2,
               const float* __restrict__ cov1, const float* __restrict__ cov2,
               float* __restrict__ out, int N)
{
    const int i = blockIdx.x * BS + threadIdx.x;
    if (i >= N) return;

    // ---- vectorized loads: 9 floats = dwordx4 + dwordx4 + dword ----
    const float* p1 = cov1 + (size_t)i * 9;
    const float* p2 = cov2 + (size_t)i * 9;
    const f32x4 a0 = *(const f32x4*)(p1);
    const f32x4 a1 = *(const f32x4*)(p1 + 4);
    const float a2 = p1[8];
    const f32x4 b0 = *(const f32x4*)(p2);
    const f32x4 b1 = *(const f32x4*)(p2 + 4);
    const float b2 = p2[8];
    const float c1[9]  = { a0[0], a0[1], a0[2], a0[3], a1[0], a1[1], a1[2], a1[3], a2 };
    const float c2r[9] = { b0[0], b0[1], b0[2], b0[3], b1[0], b1[1], b1[2], b1[3], b2 };

    const float* q1p = miu1 + (size_t)i * 3;
    const float* q2p = miu2 + (size_t)i * 3;
    const f32x2 m1v = *(const f32x2*)(q1p);
    const float m1z = q1p[2];
    const f32x2 m2v = *(const f32x2*)(q2p);
    const float m2z = q2p[2];
    const float u1[3] = { m1v[0], m1v[1], m1z };
    const float u2[3] = { m2v[0], m2v[1], m2z };

    // ---- main chain starts on c1 only (no mask dependency!) ----
    const float m00 = c1[0];
    const float m01 = 0.5f * (c1[1] + c1[3]);
    const float m02 = 0.5f * (c1[2] + c1[6]);
    const float m11 = c1[4];
    const float m12 = 0.5f * (c1[5] + c1[7]);
    const float m22 = c1[8];

    float l1, l2, l3;
    eigvals3(m00, m01, m02, m11, m12, m22, l1, l2, l3);
    l1 = fmaxf(l1, EIG_CLAMP); l2 = fmaxf(l2, EIG_CLAMP); l3 = fmaxf(l3, EIG_CLAMP);
    const float sa = sqrt_fast(l1), sb = sqrt_fast(l2), sc = sqrt_fast(l3);
    const float i_ab = rcp_fast(sa + sb);
    const float i_bc = rcp_fast(sb + sc);
    const float i_ac = rcp_fast(sa + sc);
    const float ea = rcp_fast(INV_EPS + sa);
    const float eb = rcp_fast(INV_EPS + sb);
    const float ec = rcp_fast(INV_EPS + sc);
    // Newton coefficients for f=sqrt (q*) and f=1/(eps+sqrt) (g*), packed.
    const v2f qg0 = mk2(sa, ea);
    const v2f qg1 = mk2(i_ab, -ea * eb * i_ab);
    const v2f qg2 = mk2(-i_ab * i_bc * i_ac,
                        (INV_EPS + sa + sb + sc) * ea * eb * ec * i_ab * i_bc * i_ac);

    // U = M - l1*I, V = M - l2*I, P = U*V (symmetric)
    const float u00 = m00 - l1, u11 = m11 - l1, u22 = m22 - l1;
    const float v00 = m00 - l2, v11 = m11 - l2, v22 = m22 - l2;
    const v2f PA = u00 * mk2(v00, m01) + m01 * mk2(m01, v11) + m02 * mk2(m02, m12); // P00,P01
    const v2f PB = mk2(u00, m01) * mk2(m02, m01) + mk2(m01, u11) * mk2(m12, v11)
                 + mk2(m02, m12) * mk2(v22, m12);                                    // P02,P11
    const v2f PC = mk2(m01, m02) * mk2(m02, m02) + mk2(u11, m12) * mk2(m12, m12)
                 + mk2(m12, u22) * mk2(v22, v22);                                    // P12,P22

    // A_sqrt (S) and A_sqrt_inv (G) share the Newton basis: pack (S_ij, G_ij)
    const v2f SG00 = qg0 + qg1 * u00 + qg2 * PA[0];
    const v2f SG01 =       qg1 * m01 + qg2 * PA[1];
    const v2f SG02 =       qg1 * m02 + qg2 * PB[0];
    const v2f SG11 = qg0 + qg1 * u11 + qg2 * PB[1];
    const v2f SG12 =       qg1 * m12 + qg2 * PC[0];
    const v2f SG22 = qg0 + qg1 * u22 + qg2 * PC[1];
    const float S00 = SG00[0], G00 = SG00[1];
    const float S01 = SG01[0], G01 = SG01[1];
    const float S02 = SG02[0], G02 = SG02[1];
    const float S11 = SG11[0], G11 = SG11[1];
    const float S12 = SG12[0], G12 = SG12[1];
    const float S22 = SG22[0], G22 = SG22[1];

    // D = sym(c2) — first use of c2 (its load latency hidden under eig1)
    const float d00 = c2r[0];
    const float d01 = 0.5f * (c2r[1] + c2r[3]);
    const float d02 = 0.5f * (c2r[2] + c2r[6]);
    const float d11 = c2r[4];
    const float d12 = 0.5f * (c2r[5] + c2r[7]);
    const float d22 = c2r[8];

    // T = S*D (full), C = T*S (6 unique)
    const v2f TA = S00 * mk2(d00, d01) + S01 * mk2(d01, d11) + S02 * mk2(d02, d12); // T00,T01
    const v2f TB = mk2(S00, S01) * mk2(d02, d00) + mk2(S01, S11) * mk2(d12, d01)
                 + mk2(S02, S12) * mk2(d22, d02);                                    // T02,T10
    const v2f TC = S01 * mk2(d01, d02) + S11 * mk2(d11, d12) + S12 * mk2(d12, d22); // T11,T12
    const v2f TD = S02 * mk2(d00, d01) + S12 * mk2(d01, d11) + S22 * mk2(d02, d12); // T20,T21
    const float T00 = TA[0], T01 = TA[1], T02 = TB[0], T10 = TB[1];
    const float T11 = TC[0], T12 = TC[1], T20 = TD[0], T21 = TD[1];
    const float T22 = S02 * d02 + S12 * d12 + S22 * d22;

    const v2f CA = T00 * mk2(S00, S01) + T01 * mk2(S01, S11) + T02 * mk2(S02, S12); // C00,C01
    const v2f CB = mk2(T00, T10) * mk2(S02, S01) + mk2(T01, T11) * mk2(S12, S11)
                 + mk2(T02, T12) * mk2(S22, S12);                                    // C02,C11
    const v2f CC = mk2(T10, T20) * S02 + mk2(T11, T21) * S12 + mk2(T12, T22) * S22; // C12,C22
    const float C00 = CA[0], C01 = CA[1], C02 = CB[0];
    const float C11 = CB[1], C12 = CC[0], C22 = CC[1];

    // C_sqrt: f(lambda) = sqrt(|lambda|)
    float e1, e2, e3;
    eigvals3(C00, C01, C02, C11, C12, C22, e1, e2, e3);
    const float ra = sqrt_fast(fabsf(e1));
    const float rb = sqrt_fast(fabsf(e2));
    const float rc = sqrt_fast(fabsf(e3));
    const float j_ab = rcp_fast(fmaxf(ra + rb, 1e-12f));
    const float j_bc = rcp_fast(fmaxf(rb + rc, 1e-12f));
    const float j_ac = rcp_fast(fmaxf(ra + rc, 1e-12f));
    const float h0 = ra, h1 = j_ab, h2 = -j_ab * j_bc * j_ac;
    const float cu00 = C00 - e1, cu11 = C11 - e1, cu22 = C22 - e1;
    const float cv00 = C00 - e2, cv11 = C11 - e2, cv22 = C22 - e2;
    const v2f RA = cu00 * mk2(cv00, C01) + C01 * mk2(C01, cv11) + C02 * mk2(C02, C12); // R00,R01
    const v2f RB = mk2(cu00, C01) * mk2(C02, C01) + mk2(C01, cu11) * mk2(C12, cv11)
                 + mk2(C02, C12) * mk2(cv22, C12);                                      // R02,R11
    const v2f RC = mk2(C01, C02) * mk2(C02, C02) + mk2(cu11, C12) * mk2(C12, C12)
                 + mk2(C12, cu22) * mk2(cv22, cv22);                                    // R12,R22

    const v2f XA = mk2(h0, 0.0f) + h1 * mk2(cu00, C01) + h2 * mk2(RA[0], RA[1]); // X00,X01
    const v2f XB = mk2(h0, 0.0f) + h1 * mk2(cu11, C02) + h2 * mk2(RB[1], RB[0]); // X11,X02
    const v2f XC = mk2(h0, 0.0f) + h1 * mk2(cu22, C12) + h2 * mk2(RC[1], RC[0]); // X22,X12
    const float X00 = XA[0], X01 = XA[1], X11 = XB[0], X02 = XB[1];
    const float X22 = XC[0], X12 = XC[1];

    // A = S * X, W = A * G
    const v2f AA = S00 * mk2(X00, X01) + S01 * mk2(X01, X11) + S02 * mk2(X02, X12); // A00,A01
    const v2f AB = mk2(S00, S01) * mk2(X02, X00) + mk2(S01, S11) * mk2(X12, X01)
                 + mk2(S02, S12) * mk2(X22, X02);                                    // A02,A10
    const v2f AC = S01 * mk2(X01, X02) + S11 * mk2(X11, X12) + S12 * mk2(X12, X22); // A11,A12
    const v2f AD = S02 * mk2(X00, X01) + S12 * mk2(X01, X11) + S22 * mk2(X02, X12); // A20,A21
    const float A00 = AA[0], A01 = AA[1], A02 = AB[0], A10 = AB[1];
    const float A11 = AC[0], A12 = AC[1], A20 = AD[0], A21 = AD[1];
    const float A22 = S02 * X02 + S12 * X12 + S22 * X22;

    const v2f WA = A00 * mk2(G00, G01) + A01 * mk2(G01, G11) + A02 * mk2(G02, G12); // W0,W1
    const v2f WB = mk2(A00, A10) * mk2(G02, G00) + mk2(A01, A11) * mk2(G12, G01)
                 + mk2(A02, A12) * mk2(G22, G02);                                    // W2,W3
    const v2f WC = A10 * mk2(G01, G02) + A11 * mk2(G11, G12) + A12 * mk2(G12, G22); // W4,W5
    const v2f WD = A20 * mk2(G00, G01) + A21 * mk2(G01, G11) + A22 * mk2(G02, G12); // W6,W7
    const float W0 = WA[0], W1 = WA[1], W2 = WB[0], W3 = WB[1];
    const float W4 = WC[0], W5 = WC[1], W6 = WD[0], W7 = WD[1];
    const float W8 = A20 * G02 + A21 * G12 + A22 * G22;

    // cov_vel = W + W^T - 2*sym(cov_1): 6 unique entries
    const v2f EA = mk2(W0, W1) + mk2(W0, W3) - 2.0f * mk2(m00, m01); // E00,E01
    const v2f EB = mk2(W2, W4) + mk2(W6, W4) - 2.0f * mk2(m02, m11); // E02,E11
    const v2f EC = mk2(W5, W8) + mk2(W7, W8) - 2.0f * mk2(m12, m22); // E12,E22

    // ---- stability mask (independent of the chain; computed in parallel) ----
    float amax1 = 0.0f, amax2 = 0.0f, amin1 = 1e30f, amin2 = 1e30f;
    #pragma unroll
    for (int k = 0; k < 9; ++k) {
        amax1 = fmaxf(amax1, fabsf(c1[k]));  amin1 = fminf(amin1, fabsf(c1[k]));
        amax2 = fmaxf(amax2, fabsf(c2r[k])); amin2 = fminf(amin2, fabsf(c2r[k]));
    }
    bool ok = (amax1 < MAX_COV) && (amax2 < MAX_COV)
           && (amin1 > MIN_COV) && (amin2 > MIN_COV);
    const float sdv = fmaxf(fmaxf(fabsf(c1[1] - c1[3]), fabsf(c1[2] - c1[6])),
                     fmaxf(fabsf(c1[5] - c1[7]),
                     fmaxf(fmaxf(fabsf(c2r[1] - c2r[3]), fabsf(c2r[2] - c2r[6])),
                           fabsf(c2r[5] - c2r[7]))));
    ok = ok && (sdv < SYMM_THRESH);
    const float det1 = c1[0] * (c1[4] * c1[8] - c1[5] * c1[7])
                     - c1[1] * (c1[3] * c1[8] - c1[5] * c1[6])
                     + c1[2] * (c1[3] * c1[7] - c1[4] * c1[6]);
    const float det2 = c2r[0] * (c2r[4] * c2r[8] - c2r[5] * c2r[7])
                     - c2r[1] * (c2r[3] * c2r[8] - c2r[5] * c2r[6])
                     + c2r[2] * (c2r[3] * c2r[7] - c2r[4] * c2r[6]);
    ok = ok && (fabsf(det1) > DET_THRESH) && (fabsf(det2) > DET_THRESH);
    const float um = fmaxf(fmaxf(fmaxf(fabsf(u1[0]), fabsf(u1[1])), fabsf(u1[2])),
                           fmaxf(fmaxf(fabsf(u2[0]), fabsf(u2[1])), fabsf(u2[2])));
    ok = ok && (um < MAX_POS);

    const float E00 = ok ? EA[0] : 0.0f;
    const float E01 = ok ? EA[1] : 0.0f;
    const float E02 = ok ? EB[0] : 0.0f;
    const float E11 = ok ? EB[1] : 0.0f;
    const float E12 = ok ? EC[0] : 0.0f;
    const float E22 = ok ? EC[1] : 0.0f;

    // ---- vectorized stores (regular, write-back cached) ----
    float* out_cov = out + (size_t)N * 3;
    float* oc = out_cov + (size_t)i * 9;
    f32x4 o0; o0[0] = E00; o0[1] = E01; o0[2] = E02; o0[3] = E01;
    f32x4 o1; o1[0] = E11; o1[1] = E12; o1[2] = E02; o1[3] = E12;
    *(f32x4*)oc       = o0;
    *(f32x4*)(oc + 4) = o1;
    oc[8] = E22;

    float* om = out + (size_t)i * 3;
    f32x2 mo; mo[0] = ok ? (u2[0] - u1[0]) : 0.0f;
              mo[1] = ok ? (u2[1] - u1[1]) : 0.0f;
    *(f32x2*)om = mo;
    om[2] = ok ? (u2[2] - u1[2]) : 0.0f;
}

} // namespace

extern "C" void kernel_launch(void* const* d_in, const int* in_sizes, int n_in,
                              void* d_out, int out_size, void* d_ws, size_t ws_size,
                              hipStream_t stream)
{
    const float* miu1 = (const float*)d_in[0];
    const float* miu2 = (const float*)d_in[1];
    const float* cov1 = (const float*)d_in[2];
    const float* cov2 = (const float*)d_in[3];
    float* out = (float*)d_out;
    const int N = in_sizes[0] / 3;
    const int grid = (N + BS - 1) / BS;
    hipLaunchKernelGGL(wl_kernel, dim3(grid), dim3(BS), 0, stream,
                       miu1, miu2, cov1, cov2, out, N);
}